// Round 4
// baseline (81.267 us; speedup 1.0000x reference)
//
#include <hip/hip_runtime.h>
#include <math.h>

#define BB 32
#define CC 512
#define CR 32
#define HWN 3136
#define HW4 784   // HWN / 4  (= 12*64 + 16)

typedef float f32x4 __attribute__((ext_vector_type(4)));

// ---------------------------------------------------------------------------
// Kernel 1: ONE WAVE per (b,c) plane-pair (4 waves / 256-thread block):
//   - sum of xr plane, sum of xi plane  -> means ar, ai
//   - argmax over hw of score^2 = zr^2 + zi^2 (sqrt dropped: monotonic),
//     best (r,q) values carried through the butterfly reduce -> no gather.
//
// score^2 = d + 2(r^2-q^2)/d + 1/d... derived:
//   zr^2+zi^2 = d + 2(r^2-q^2)*u + d*u^2 = fma(fma(d,u, 2(r^2-q^2)), u, d),
//   u = 1/d via fast rcp (argmax only; outputs are exact carried values).
// ---------------------------------------------------------------------------
__global__ __launch_bounds__(256) void cg_reduce_kernel(
    const float* __restrict__ x,
    float* __restrict__ ar, float* __restrict__ ai,
    float* __restrict__ mr, float* __restrict__ mi)
{
    const int wid  = (blockIdx.x << 2) | (threadIdx.x >> 6);  // bc = 0..B*C-1
    const int lane = threadIdx.x & 63;
    const int b = wid >> 9;               // / CC
    const int c = wid & (CC - 1);
    const float* xr = x + (size_t)((b << 10) + c) * HWN;      // (b*2C + c)
    const float* xi = xr + (size_t)CC * HWN;
    const f32x4* xr4 = (const f32x4*)xr;
    const f32x4* xi4 = (const f32x4*)xi;

    float sr = 0.0f, si = 0.0f;
    float bs = -1.0f;                     // best score^2 (>= 0 always wins)
    int   bix = 0;
    float br = 0.0f, bq = 0.0f;           // values at best index

#pragma unroll 4
    for (int it = 0; it < 12; ++it) {
        const int v = lane + (it << 6);
        f32x4 r4 = __builtin_nontemporal_load(&xr4[v]);
        f32x4 i4 = __builtin_nontemporal_load(&xi4[v]);
#pragma unroll
        for (int k = 0; k < 4; ++k) {
            float r = r4[k], q = i4[k];
            sr += r; si += q;
            float r2 = r * r, q2 = q * q;
            float d  = r2 + q2;
            float u  = __builtin_amdgcn_rcpf(d);
            float s  = fmaf(fmaf(d, u, 2.0f * (r2 - q2)), u, d);
            if (s > bs) { bs = s; bix = v * 4 + k; br = r; bq = q; }
        }
    }
    if (lane < 16) {                      // tail: v = 768 + lane
        const int v = 768 + lane;
        f32x4 r4 = __builtin_nontemporal_load(&xr4[v]);
        f32x4 i4 = __builtin_nontemporal_load(&xi4[v]);
#pragma unroll
        for (int k = 0; k < 4; ++k) {
            float r = r4[k], q = i4[k];
            sr += r; si += q;
            float r2 = r * r, q2 = q * q;
            float d  = r2 + q2;
            float u  = __builtin_amdgcn_rcpf(d);
            float s  = fmaf(fmaf(d, u, 2.0f * (r2 - q2)), u, d);
            if (s > bs) { bs = s; bix = v * 4 + k; br = r; bq = q; }
        }
    }

    // 64-lane butterfly reduce; ties -> min index (jnp.argmax first-hit)
#pragma unroll
    for (int m = 1; m < 64; m <<= 1) {
        sr += __shfl_xor(sr, m);
        si += __shfl_xor(si, m);
        float os = __shfl_xor(bs, m);
        int   oi = __shfl_xor(bix, m);
        float orr = __shfl_xor(br, m);
        float oq = __shfl_xor(bq, m);
        if (os > bs || (os == bs && oi < bix)) { bs = os; bix = oi; br = orr; bq = oq; }
    }

    if (lane == 0) {
        ar[wid] = sr * (1.0f / HWN);
        ai[wid] = si * (1.0f / HWN);
        mr[wid] = br;
        mi[wid] = bq;
    }
}

// ---------------------------------------------------------------------------
// Kernel 2: both complex MLPs + sum, one block per batch row.
//   att = MLP(ar,ai) + MLP(mr,mi);  out[b, 0:C] = re, out[b, C:2C] = im
// ---------------------------------------------------------------------------
__global__ __launch_bounds__(256) void cg_mlp_kernel(
    const float* __restrict__ ar, const float* __restrict__ ai,
    const float* __restrict__ mr, const float* __restrict__ mi,
    const float* __restrict__ w1r, const float* __restrict__ b1r,
    const float* __restrict__ w1i, const float* __restrict__ b1i,
    const float* __restrict__ w2r, const float* __restrict__ b2r,
    const float* __restrict__ w2i, const float* __restrict__ b2i,
    float* __restrict__ out)
{
    __shared__ __align__(16) float s_re[2][CC], s_im[2][CC];
    __shared__ float h_re[2][CR], h_im[2][CR];

    const int b = blockIdx.x;
    const int t = threadIdx.x;

    if (t < 128) {
        ((f32x4*)s_re[0])[t] = ((const f32x4*)(ar + b * CC))[t];
        ((f32x4*)s_im[0])[t] = ((const f32x4*)(ai + b * CC))[t];
        ((f32x4*)s_re[1])[t] = ((const f32x4*)(mr + b * CC))[t];
        ((f32x4*)s_im[1])[t] = ((const f32x4*)(mi + b * CC))[t];
    }
    __syncthreads();

    // ---- layer 1 + cardioid: 64 tasks (m,j), 4 threads per task ----
    {
        const int task = t >> 2;          // 0..63
        const int part = t & 3;
        const int m = task >> 5;          // 0..1  (which MLP input)
        const int j = task & 31;          // hidden unit
        const f32x4* wr4 = (const f32x4*)(w1r + j * CC + part * 128);
        const f32x4* wi4 = (const f32x4*)(w1i + j * CC + part * 128);
        const f32x4* re4 = (const f32x4*)(&s_re[m][part * 128]);
        const f32x4* im4 = (const f32x4*)(&s_im[m][part * 128]);
        float d_rr = 0.f, d_ir = 0.f, d_ri = 0.f, d_ii = 0.f;
#pragma unroll 8
        for (int k = 0; k < 32; ++k) {
            f32x4 re = re4[k], im = im4[k], vr = wr4[k], vi = wi4[k];
#pragma unroll
            for (int kk = 0; kk < 4; ++kk) {
                d_rr += re[kk] * vr[kk];
                d_ir += im[kk] * vr[kk];
                d_ri += re[kk] * vi[kk];
                d_ii += im[kk] * vi[kk];
            }
        }
        d_rr += __shfl_xor(d_rr, 1); d_rr += __shfl_xor(d_rr, 2);
        d_ir += __shfl_xor(d_ir, 1); d_ir += __shfl_xor(d_ir, 2);
        d_ri += __shfl_xor(d_ri, 1); d_ri += __shfl_xor(d_ri, 2);
        d_ii += __shfl_xor(d_ii, 1); d_ii += __shfl_xor(d_ii, 2);
        if (part == 0) {
            float hre = d_rr + b1r[j] - d_ii - b1i[j];
            float him = d_ir + b1r[j] + d_ri + b1i[j];
            // cardioid: s = 0.5*(1 + cos(atan2(im,re))) = 0.5*(1 + re/|z|)
            float n2 = hre * hre + him * him;
            float s  = (n2 > 0.0f) ? 0.5f * (1.0f + hre * rsqrtf(n2)) : 1.0f;
            h_re[m][j] = hre * s;
            h_im[m][j] = him * s;
        }
    }
    __syncthreads();

    // ---- layer 2 (summed over both MLPs) ----
    for (int j = t; j < CC; j += 256) {
        float o_re = 2.0f * (b2r[j] - b2i[j]);   // bias applied per MLP (x2)
        float o_im = 2.0f * (b2r[j] + b2i[j]);
        const f32x4* wr4 = (const f32x4*)(w2r + j * CR);
        const f32x4* wi4 = (const f32x4*)(w2i + j * CR);
#pragma unroll
        for (int m = 0; m < 2; ++m) {
            const float* hr_ = h_re[m];
            const float* hi_ = h_im[m];
#pragma unroll
            for (int kv = 0; kv < 8; ++kv) {
                f32x4 vr = wr4[kv], vi = wi4[kv];
#pragma unroll
                for (int kk = 0; kk < 4; ++kk) {
                    float hr = hr_[kv * 4 + kk], hi = hi_[kv * 4 + kk];
                    o_re += hr * vr[kk] - hi * vi[kk];
                    o_im += hi * vr[kk] + hr * vi[kk];
                }
            }
        }
        out[b * 2 * CC + j]      = o_re;
        out[b * 2 * CC + CC + j] = o_im;
    }
}

extern "C" void kernel_launch(void* const* d_in, const int* in_sizes, int n_in,
                              void* d_out, int out_size, void* d_ws, size_t ws_size,
                              hipStream_t stream)
{
    const float* x   = (const float*)d_in[0];
    const float* w1r = (const float*)d_in[1];
    const float* b1r = (const float*)d_in[2];
    const float* w1i = (const float*)d_in[3];
    const float* b1i = (const float*)d_in[4];
    const float* w2r = (const float*)d_in[5];
    const float* b2r = (const float*)d_in[6];
    const float* w2i = (const float*)d_in[7];
    const float* b2i = (const float*)d_in[8];

    float* ws = (float*)d_ws;
    float* ar = ws;
    float* ai = ws + BB * CC;
    float* mr = ws + 2 * BB * CC;
    float* mi = ws + 3 * BB * CC;

    cg_reduce_kernel<<<BB * CC / 4, 256, 0, stream>>>(x, ar, ai, mr, mi);
    cg_mlp_kernel<<<BB, 256, 0, stream>>>(ar, ai, mr, mi,
                                          w1r, b1r, w1i, b1i,
                                          w2r, b2r, w2i, b2i,
                                          (float*)d_out);
}